// Round 14
// baseline (920.806 us; speedup 1.0000x reference)
//
#include <hip/hip_runtime.h>

namespace {

constexpr int NR = 8192;
constexpr int DD = 512;
constexpr int NSPLIT = 4;
constexpr int KVLEN = NR / NSPLIT;   // 2048
constexpr int KT = 32;               // kv tile
constexpr int NT = KVLEN / KT;       // 64 tiles
constexpr int QB = 32;               // q rows per block (v6: halved for occupancy)
constexpr float SCALE = 0.04419417382415922f;  // 1/sqrt(512)

typedef __bf16 bf16x8 __attribute__((ext_vector_type(8)));
typedef __bf16 bf16x4 __attribute__((ext_vector_type(4)));
typedef float  f32x16 __attribute__((ext_vector_type(16)));
typedef float  f32x4  __attribute__((ext_vector_type(4)));

__device__ __forceinline__ f32x16 mfma32(bf16x8 a, bf16x8 b, f32x16 c) {
    return __builtin_amdgcn_mfma_f32_32x32x16_bf16(a, b, c, 0, 0, 0);
}
__device__ __forceinline__ f32x4 mfma16(bf16x8 a, bf16x8 b, f32x4 c) {
    return __builtin_amdgcn_mfma_f32_16x16x32_bf16(a, b, c, 0, 0, 0);
}

typedef const __attribute__((address_space(1))) void g_void;
typedef __attribute__((address_space(3))) void l_void;
__device__ __forceinline__ void lds_dma16(const void* g, void* l) {
    __builtin_amdgcn_global_load_lds((g_void*)g, (l_void*)l, 16, 0, 0);
}

__device__ __forceinline__ bf16x8 cvt8(float4 a, float4 b) {
    bf16x8 o;
    o[0] = (__bf16)a.x; o[1] = (__bf16)a.y; o[2] = (__bf16)a.z; o[3] = (__bf16)a.w;
    o[4] = (__bf16)b.x; o[5] = (__bf16)b.y; o[6] = (__bf16)b.z; o[7] = (__bf16)b.w;
    return o;
}

// K packed as 32KB tile images that ARE the desired (swizzled) LDS layout:
// elem(tile, kv, d) = tile*16384 + kv*512 + ((d>>3) ^ (kv&7))*8 + (d&7)
__device__ __forceinline__ size_t kfa(int n, int d) {
    int tile = n >> 5, kv = n & 31;
    int chunk = (d >> 3) ^ (kv & 7);
    return (size_t)tile * 16384 + kv * 512 + chunk * 8 + (d & 7);
}
// V frag-major: flash PV reads chunk*512 + lane*8 contiguously.
__device__ __forceinline__ size_t vfa(int n, int d) {
    size_t chunk = (size_t)(((n >> 5) * 4 + (d >> 7)) * 8 +
                            ((d >> 6) & 1) * 4 + ((d >> 5) & 1) * 2 + ((n >> 4) & 1));
    return chunk * 512 + ((((n >> 3) & 1) * 32 + (d & 31)) * 8) + (n & 7);
}

// ---------------- adj -> bitmask (u32 per 32 kv) ----------------
__global__ void __launch_bounds__(256)
bitpack_kernel(const int* __restrict__ adj, unsigned* __restrict__ abits) {
    const int w = threadIdx.x >> 6, lane = threadIdx.x & 63;
    const int q = blockIdx.x * 4 + w;
    const int* row = adj + (size_t)q * NR;
    unsigned* orow = abits + (size_t)q * 256;
    for (int i = 0; i < 128; ++i) {
        unsigned long long m = __ballot(row[i * 64 + lane] != 0);
        if (lane == 0) { orow[2 * i] = (unsigned)m; orow[2 * i + 1] = (unsigned)(m >> 32); }
    }
}

// ---------------- GEMM C = A * B^T  (M=8192, N=512, K=512), fused fp32->bf16 staging --------
template<bool FINAL>
__global__ void __launch_bounds__(256, 2)
gemm_kernel(const float* __restrict__ Xf, const __bf16* __restrict__ Aop,
            const float* __restrict__ B0, const float* __restrict__ B1,
            const float* __restrict__ B2,
            __bf16* __restrict__ C0, __bf16* __restrict__ C1, __bf16* __restrict__ C2,
            const float* __restrict__ bias, float* __restrict__ Cf,
            const float* __restrict__ lsum)
{
    const float* B = B0;
    __bf16* Cb = C0;
    int mode = 0;
    if (!FINAL) {
        if (blockIdx.y == 1)      { B = B1; Cb = C1; mode = 1; }
        else if (blockIdx.y == 2) { B = B2; Cb = C2; }
    }
    __shared__ __bf16 As[128][72];
    __shared__ __bf16 Bs[128][72];
    const int t = threadIdx.x;
    const int w = t >> 6, lane = t & 63, lo = lane & 31, hi = lane >> 5;
    const int wm = w >> 1, wn = w & 1;
    const int bm = (blockIdx.x >> 2) * 128;
    const int bn = (blockIdx.x & 3) * 128;

    f32x16 acc[2][2];
    #pragma unroll
    for (int a = 0; a < 2; ++a)
        #pragma unroll
        for (int b = 0; b < 2; ++b)
            #pragma unroll
            for (int r = 0; r < 16; ++r) acc[a][b][r] = 0.f;

    for (int k0 = 0; k0 < DD; k0 += 64) {
        __syncthreads();
        #pragma unroll
        for (int pp = 0; pp < 2; ++pp) {
            int r = pp * 64 + (t >> 2), c = (t & 3) * 16;
            if (FINAL) {
                int row = bm + r;
                float l0 = lsum[row], l1 = lsum[NR + row],
                      l2 = lsum[2 * NR + row], l3 = lsum[3 * NR + row];
                float Winv = 1.f / (l0 + l1 + l2 + l3);
                float w0 = l0 * Winv, w1 = l1 * Winv, w2 = l2 * Winv, w3 = l3 * Winv;
                const size_t stride = (size_t)NR * DD;
                #pragma unroll
                for (int cc = 0; cc < 2; ++cc) {
                    const size_t base = (size_t)row * DD + k0 + c + cc * 8;
                    bf16x8 o0 = *(const bf16x8*)(Aop + base);
                    bf16x8 o1 = *(const bf16x8*)(Aop + stride + base);
                    bf16x8 o2 = *(const bf16x8*)(Aop + 2 * stride + base);
                    bf16x8 o3 = *(const bf16x8*)(Aop + 3 * stride + base);
                    bf16x8 om;
                    #pragma unroll
                    for (int e = 0; e < 8; ++e)
                        om[e] = (__bf16)(w0 * (float)o0[e] + w1 * (float)o1[e] +
                                         w2 * (float)o2[e] + w3 * (float)o3[e]);
                    *(bf16x8*)&As[r][c + cc * 8] = om;
                }
            } else {
                const float* asrc = Xf + (size_t)(bm + r) * DD + k0 + c;
                float4 a0 = *(const float4*)(asrc);
                float4 a1 = *(const float4*)(asrc + 4);
                float4 a2 = *(const float4*)(asrc + 8);
                float4 a3 = *(const float4*)(asrc + 12);
                *(bf16x8*)&As[r][c]     = cvt8(a0, a1);
                *(bf16x8*)&As[r][c + 8] = cvt8(a2, a3);
            }
            const float* bsrc = B + (size_t)(bn + r) * DD + k0 + c;
            float4 b0 = *(const float4*)(bsrc);
            float4 b1 = *(const float4*)(bsrc + 4);
            float4 b2 = *(const float4*)(bsrc + 8);
            float4 b3 = *(const float4*)(bsrc + 12);
            *(bf16x8*)&Bs[r][c]     = cvt8(b0, b1);
            *(bf16x8*)&Bs[r][c + 8] = cvt8(b2, b3);
        }
        __syncthreads();
        #pragma unroll
        for (int ks = 0; ks < 4; ++ks) {
            bf16x8 a0 = *(const bf16x8*)&As[wm * 64 + lo][ks * 16 + hi * 8];
            bf16x8 a1 = *(const bf16x8*)&As[wm * 64 + 32 + lo][ks * 16 + hi * 8];
            bf16x8 b0 = *(const bf16x8*)&Bs[wn * 64 + lo][ks * 16 + hi * 8];
            bf16x8 b1 = *(const bf16x8*)&Bs[wn * 64 + 32 + lo][ks * 16 + hi * 8];
            acc[0][0] = mfma32(a0, b0, acc[0][0]);
            acc[0][1] = mfma32(a0, b1, acc[0][1]);
            acc[1][0] = mfma32(a1, b0, acc[1][0]);
            acc[1][1] = mfma32(a1, b1, acc[1][1]);
        }
    }
    #pragma unroll
    for (int mi = 0; mi < 2; ++mi)
        #pragma unroll
        for (int ni = 0; ni < 2; ++ni) {
            int col = bn + wn * 64 + ni * 32 + lo;
            float bv = 0.f;
            if (FINAL) bv = bias[col];
            #pragma unroll
            for (int r = 0; r < 16; ++r) {
                int row = bm + wm * 64 + mi * 32 + (r & 3) + 8 * (r >> 2) + 4 * hi;
                if (FINAL) {
                    Cf[(size_t)row * DD + col] = acc[mi][ni][r] + bv;
                } else {
                    size_t a = (mode == 1) ? kfa(row, col) : ((size_t)row * DD + col);
                    Cb[a] = (__bf16)acc[mi][ni][r];
                }
            }
        }
}

// ---------------- repack V row-major -> frag-major (LDS transpose) ----------------
__global__ void __launch_bounds__(256)
repack_v(const __bf16* __restrict__ V, __bf16* __restrict__ VF) {
    __shared__ __bf16 tile[64][72];
    const int t = threadIdx.x;
    const int rb = blockIdx.x * 64;   // n
    const int cb = blockIdx.y * 64;   // d
    #pragma unroll
    for (int pp = 0; pp < 2; ++pp) {
        int r = pp * 32 + (t >> 3), c = (t & 7) * 8;
        *(bf16x8*)&tile[r][c] = *(const bf16x8*)(V + (size_t)(rb + r) * DD + cb + c);
    }
    __syncthreads();
    #pragma unroll
    for (int pp = 0; pp < 2; ++pp) {
        int vid = pp * 256 + t;
        int oct = vid >> 6;
        int dd = vid & 63;
        bf16x8 o;
        #pragma unroll
        for (int e = 0; e < 8; ++e) o[e] = tile[oct * 8 + e][dd];
        *(bf16x8*)(VF + vfa(rb + oct * 8, cb + dd)) = o;
    }
}

// ---------------- flash v6: QB=32, 3 waves/SIMD, single-K-buffer, 2 barriers/tile --------
// grid 1024 (256 q-blocks x 4 splits, XCD-pinned). 4 waves; wave (g=w&1, h=w>>1):
// QK-role = q-group g (16 rows, full D) x kv-half h (16 kv) via 16 mfma16, softmax
// in-register (l-partials merged at epilogue); PV-role = d-slice w*128 of all 32 q
// (O = 4 x f32x16 = 64 AGPR). Single 32 KB K buffer: B1 after QK reads -> DMA K(t+1)
// in phase B (covered by softmax+PV); B2 publishes Pl[b] + K(t+1) via counted vmcnt(1).
// LDS 37.6 KB + <=170 regs (launch_bounds 256,3) -> 3 blocks/CU = 12 waves/CU.
__global__ void __launch_bounds__(256, 3)
flash_kernel(const __bf16* __restrict__ Qg, const __bf16* __restrict__ KF,
             const __bf16* __restrict__ VF, const unsigned* __restrict__ abits,
             __bf16* __restrict__ Opart, float* __restrict__ lsum_g)
{
    __shared__ __bf16 Klds[16384];     // 32 KB single K tile (swizzled image)
    __shared__ __bf16 Pl[2][QB][40];   // 5 KB P double-buffer
    __shared__ float  llp[2][QB];      // per-kv-half l partials
    __shared__ float  lls[QB];         // summed l

    const int t = threadIdx.x;
    const int w = t >> 6, lane = t & 63;
    const int lo = lane & 31, hi = lane >> 5;   // PV indexing
    const int l15 = lane & 15, G = lane >> 4;   // QK indexing
    const int g = w & 1, h = w >> 1;            // q-group, kv-half
    const int bid = blockIdx.x;
    const int xcd = bid & 7;
    const int split = xcd >> 1;
    const int qblk = (((xcd & 1) << 7) | (bid >> 3)) * QB;
    const int kv0 = split * KVLEN;
    const int tile0 = kv0 >> 5;

    // Q B-frags for q-group g: q = qblk + g*16 + l15 ; k(d) = ks*32 + G*8 + e
    bf16x8 qa[16];
    #pragma unroll
    for (int ks = 0; ks < 16; ++ks)
        qa[ks] = *(const bf16x8*)(Qg + (size_t)(qblk + g * 16 + l15) * DD + ks * 32 + G * 8);

    f32x16 O[4];   // d = w*128 + j*32, all 32 q rows
    #pragma unroll
    for (int j = 0; j < 4; ++j)
        #pragma unroll
        for (int r = 0; r < 16; ++r) O[j][r] = 0.f;

    const unsigned* abp = abits + (size_t)(qblk + g * 16 + l15) * 256 + tile0;
    unsigned wcur = abp[0];
    float l_run = 0.f;
    const int hsw = l15 & 7;                 // K swizzle key
    const int krow = (h * 16 + l15) * 512;   // this wave's K row base

    // ---- prologue: stage K(0) ----
    #pragma unroll
    for (int i = 0; i < 8; ++i)
        lds_dma16(KF + (size_t)tile0 * 16384 + w * 4096 + i * 512 + lane * 8,
                  &Klds[w * 4096 + i * 512]);
    asm volatile("s_waitcnt vmcnt(0)" ::: "memory");
    __syncthreads();

    // ---- peeled tile 0 ----
    {
        f32x4 St;
        #pragma unroll
        for (int r = 0; r < 4; ++r) St[r] = 0.f;
        #pragma unroll
        for (int ks = 0; ks < 16; ++ks) {
            int csw = (((ks * 4 + G) ^ hsw) << 3);
            bf16x8 k = *(const bf16x8*)&Klds[krow + csw];
            St = mfma16(k, qa[ks], St);
        }
        asm volatile("s_waitcnt lgkmcnt(0)" ::: "memory");
        asm volatile("s_barrier" ::: "memory");   // B1: K(0) reads retired
        #pragma unroll
        for (int i = 0; i < 8; ++i)
            lds_dma16(KF + (size_t)(tile0 + 1) * 16384 + w * 4096 + i * 512 + lane * 8,
                      &Klds[w * 4096 + i * 512]);
        float l_add = 0.f;
        bf16x4 pv;
        #pragma unroll
        for (int r = 0; r < 4; ++r) {
            float p = ((wcur >> (h * 16 + G * 4 + r)) & 1u) ? __expf(St[r] * SCALE) : 0.f;
            l_add += p;
            pv[r] = (__bf16)p;
        }
        *(bf16x4*)&Pl[0][g * 16 + l15][h * 16 + G * 4] = pv;
        float a = l_add + __shfl_xor(l_add, 16);
        a += __shfl_xor(a, 32);
        l_run += a;
        unsigned wn = abp[1];
        asm volatile("s_waitcnt vmcnt(1) lgkmcnt(0)" ::: "memory");
        asm volatile("s_barrier" ::: "memory");   // B2: Pl[0] + K(1) published
        wcur = wn;
    }

    for (int tl = 1; tl < NT; ++tl) {
        const int b = tl & 1;
        const int tn = (tl + 1 == NT) ? 0 : tl + 1;   // wrap keeps DMA count uniform

        // ---- Phase A: QK(tl) from Kbuf (holds K(tl)) ----
        f32x4 St;
        #pragma unroll
        for (int r = 0; r < 4; ++r) St[r] = 0.f;
        #pragma unroll
        for (int ks = 0; ks < 16; ++ks) {
            int csw = (((ks * 4 + G) ^ hsw) << 3);
            bf16x8 k = *(const bf16x8*)&Klds[krow + csw];
            St = mfma16(k, qa[ks], St);
        }
        asm volatile("s_waitcnt lgkmcnt(0)" ::: "memory");
        asm volatile("s_barrier" ::: "memory");   // B1: all K(tl) reads retired

        // ---- Phase B ----
        const __bf16* vf = VF + (size_t)((tile0 + tl - 1) * 4 + w) * 4096;
        // V(tl-1) first half (chunks 0..3 -> O[0],O[1]), oldest vmem
        bf16x8 vbA0 = *(const bf16x8*)(vf + 0 * 512 + lane * 8);
        bf16x8 vbA1 = *(const bf16x8*)(vf + 1 * 512 + lane * 8);
        bf16x8 vbA2 = *(const bf16x8*)(vf + 2 * 512 + lane * 8);
        bf16x8 vbA3 = *(const bf16x8*)(vf + 3 * 512 + lane * 8);
        asm volatile("" ::: "memory");
        // K(tn) DMA into the (now free) single buffer
        #pragma unroll
        for (int i = 0; i < 8; ++i)
            lds_dma16(KF + (size_t)(tile0 + tn) * 16384 + w * 4096 + i * 512 + lane * 8,
                      &Klds[w * 4096 + i * 512]);
        // softmax(tl) in-register -> Pl[b]
        {
            float l_add = 0.f;
            bf16x4 pv;
            #pragma unroll
            for (int r = 0; r < 4; ++r) {
                float p = ((wcur >> (h * 16 + G * 4 + r)) & 1u) ? __expf(St[r] * SCALE) : 0.f;
                l_add += p;
                pv[r] = (__bf16)p;
            }
            *(bf16x4*)&Pl[b][g * 16 + l15][h * 16 + G * 4] = pv;
            float a = l_add + __shfl_xor(l_add, 16);
            a += __shfl_xor(a, 32);
            l_run += a;
        }
        // PV(tl-1): P from Pl[b^1] (published at last B2)
        bf16x8 pa0 = *(const bf16x8*)&Pl[b ^ 1][lo][hi * 8];
        bf16x8 pa1 = *(const bf16x8*)&Pl[b ^ 1][lo][16 + hi * 8];
        __builtin_amdgcn_s_setprio(1);
        O[0] = mfma32(pa0, vbA0, O[0]);
        O[0] = mfma32(pa1, vbA1, O[0]);
        O[1] = mfma32(pa0, vbA2, O[1]);
        O[1] = mfma32(pa1, vbA3, O[1]);
        __builtin_amdgcn_s_setprio(0);
        asm volatile("" ::: "memory");
        // V(tl-1) second half (chunks 4..7 -> O[2],O[3]); vbA regs now dead
        bf16x8 vbB0 = *(const bf16x8*)(vf + 4 * 512 + lane * 8);
        bf16x8 vbB1 = *(const bf16x8*)(vf + 5 * 512 + lane * 8);
        bf16x8 vbB2 = *(const bf16x8*)(vf + 6 * 512 + lane * 8);
        bf16x8 vbB3 = *(const bf16x8*)(vf + 7 * 512 + lane * 8);
        __builtin_amdgcn_s_setprio(1);
        O[2] = mfma32(pa0, vbB0, O[2]);
        O[2] = mfma32(pa1, vbB1, O[2]);
        O[3] = mfma32(pa0, vbB2, O[3]);
        O[3] = mfma32(pa1, vbB3, O[3]);
        __builtin_amdgcn_s_setprio(0);
        unsigned wn = abp[tn];
        // K DMAs (older) must land block-wide; wn (newest) may stay in flight.
        asm volatile("s_waitcnt vmcnt(1) lgkmcnt(0)" ::: "memory");
        asm volatile("s_barrier" ::: "memory");   // B2: Pl[b] + K(tn) published
        wcur = wn;
    }

    // ---- epilogue PV(NT-1) ----
    {
        const int b = (NT - 1) & 1;
        bf16x8 pa0 = *(const bf16x8*)&Pl[b][lo][hi * 8];
        bf16x8 pa1 = *(const bf16x8*)&Pl[b][lo][16 + hi * 8];
        const __bf16* vf = VF + (size_t)((tile0 + NT - 1) * 4 + w) * 4096;
        #pragma unroll
        for (int j = 0; j < 4; ++j) {
            bf16x8 v0 = *(const bf16x8*)(vf + (j * 2 + 0) * 512 + lane * 8);
            bf16x8 v1 = *(const bf16x8*)(vf + (j * 2 + 1) * 512 + lane * 8);
            O[j] = mfma32(pa0, v0, O[j]);
            O[j] = mfma32(pa1, v1, O[j]);
        }
    }
    // ---- l partials -> lls; publish lsum ----
    if (lane < 16) llp[h][g * 16 + lane] = l_run;
    __syncthreads();
    if (t < QB) {
        float s = llp[0][t] + llp[1][t];
        lls[t] = s;
        lsum_g[(size_t)split * NR + qblk + t] = s;
    }
    __syncthreads();
    // ---- normalize + store Opart ----
    #pragma unroll
    for (int g4 = 0; g4 < 4; ++g4) {
        float4 lv = *(const float4*)&lls[g4 * 8 + 4 * hi];
        #pragma unroll
        for (int e = 0; e < 4; ++e) {
            float lval = (&lv.x)[e];
            float inv = (lval > 0.f) ? 1.f / lval : 0.f;
            int row = qblk + g4 * 8 + 4 * hi + e;
            #pragma unroll
            for (int j = 0; j < 4; ++j) {
                int col = w * 128 + j * 32 + lo;
                Opart[(size_t)split * NR * DD + (size_t)row * DD + col] =
                    (__bf16)(O[j][g4 * 4 + e] * inv);
            }
        }
    }
}

} // namespace

extern "C" void kernel_launch(void* const* d_in, const int* in_sizes, int n_in,
                              void* d_out, int out_size, void* d_ws, size_t ws_size,
                              hipStream_t stream)
{
    (void)in_sizes; (void)n_in; (void)out_size; (void)ws_size;
    const float* X  = (const float*)d_in[0];
    const int*   adj = (const int*)d_in[1];
    const float* Wq = (const float*)d_in[2];
    const float* Wk = (const float*)d_in[3];
    const float* Wv = (const float*)d_in[4];
    const float* Wo = (const float*)d_in[5];
    const float* bo = (const float*)d_in[6];
    float* out = (float*)d_out;

    char* ws = (char*)d_ws;
    __bf16* Qb   = (__bf16*)(ws + 0);          // 8192x512 row-major (8.39 MB)
    __bf16* KFb  = (__bf16*)(ws + 8388608);    // swizzled K tile images (8.39 MB)
    __bf16* VFb  = (__bf16*)(ws + 16777216);   // frag-major V (8.39 MB)
    unsigned* abits = (unsigned*)(ws + 25165824);  // 8192x256 u32 (8.39 MB)
    __bf16* Vb   = (__bf16*)(ws + 33554432);   // row-major V (dead after repack; inside Op)
    __bf16* Op   = (__bf16*)(ws + 33554432);   // 4x8192x512 bf16 (33.55 MB)
    float*  lseb = (float*)(ws + 67108864);    // 4x8192 f32

    bitpack_kernel<<<2048, 256, 0, stream>>>(adj, abits);
    gemm_kernel<false><<<dim3(256, 3), 256, 0, stream>>>(X, nullptr, Wq, Wk, Wv,
                                                         Qb, KFb, Vb,
                                                         nullptr, nullptr, nullptr);
    repack_v<<<dim3(128, 8), 256, 0, stream>>>(Vb, VFb);
    flash_kernel<<<1024, 256, 0, stream>>>(Qb, KFb, VFb, abits, Op, lseb);
    gemm_kernel<true><<<dim3(256, 1), 256, 0, stream>>>(nullptr, Op, Wo, nullptr, nullptr,
                                                        nullptr, nullptr, nullptr,
                                                        bo, out, lseb);
}